// Round 2
// baseline (159.681 us; speedup 1.0000x reference)
//
#include <hip/hip_runtime.h>

typedef __attribute__((ext_vector_type(4))) float          f32x4;
typedef __attribute__((ext_vector_type(4))) unsigned int   u32x4;
typedef __attribute__((ext_vector_type(4))) unsigned short u16x4;

#define PI_F 3.14159265358979f

// round-to-nearest-even fp32 -> bf16
__device__ __forceinline__ unsigned short f2bf(float f) {
    unsigned int x = __float_as_uint(f);
    unsigned int r = ((x >> 16) & 1u) + 0x7fffu;
    return (unsigned short)((x + r) >> 16);
}

__device__ __forceinline__ void mfma16(f32x4& c, u32x4 a, u32x4 b) {
    asm volatile("v_mfma_f32_16x16x32_bf16 %0, %1, %2, %0"
                 : "+v"(c) : "v"(a), "v"(b));
}

// ---------------- prep kernels ----------------

// H[u][i][j] = h_u((i-j) mod 256), bf16.
__global__ void hbuild(unsigned short* __restrict__ H) {
    const int US[8] = {5, 22, 39, 57, 74, 92, 109, 127};
    int idx = blockIdx.x * 256 + threadIdx.x;
    int u = idx >> 16;
    int i = (idx >> 8) & 255, j = idx & 255;
    int d = (i - j) & 255;
    int m = 2 * US[u] + 1;
    float h;
    if (d == 0) {
        h = (float)m * (1.0f / 256.0f);
    } else {
        int t = (m * d) & 511;  // sin(pi*m*d/256) has period 512 in (m*d)
        float num = sinf((float)t * (PI_F / 256.0f));
        float den = sinf((float)d * (PI_F / 256.0f));
        h = num / (256.0f * den);
    }
    H[idx] = f2bf(h);
}

// x fp32 -> Xb bf16 (vectorized by 4); optionally write channel 0 of out.
__global__ void xconv(const float* __restrict__ x, unsigned short* __restrict__ Xb,
                      float* __restrict__ out, int write_c0) {
    int idx = blockIdx.x * 256 + threadIdx.x;  // 1,048,576 total
    f32x4 v = ((const f32x4*)x)[idx];
    u16x4 o = { f2bf(v.x), f2bf(v.y), f2bf(v.z), f2bf(v.w) };
    ((u16x4*)Xb)[idx] = o;
    if (write_c0) {
        size_t g = (size_t)idx * 4;
        out[(g + 0) * 9] = v.x;
        out[(g + 1) * 9] = v.y;
        out[(g + 2) * 9] = v.z;
        out[(g + 3) * 9] = v.w;
    }
}

// LDS XOR swizzle: tiles [rows][128 bytes], spread column-slices across banks.
#define SWZ(r, cb) (((unsigned)(r) * 128u) + ((unsigned)(cb) ^ ((((unsigned)(r)) & 7u) << 4)))

// ---------------- 128x128 GEMM core (used by stage1 + fallback stage2) -------
__device__ __forceinline__ void gemm_core(const char* __restrict__ Ab,
                                          const char* __restrict__ Bb,
                                          char* sA, char* sB, f32x4 acc[4][4]) {
    const int tid  = threadIdx.x;
    const int lane = tid & 63;
    const int wm   = (tid >> 7) & 1;
    const int wn   = (tid >> 6) & 1;
    const int lrow = lane & 15;
    const int lk   = lane >> 4;

    for (int kt = 0; kt < 4; ++kt) {   // K=256, BK=64
        if (kt) __syncthreads();
        u32x4 va[4], vb[4];
#pragma unroll
        for (int q = 0; q < 4; ++q) {
            int id = q * 256 + tid;
            int r = id >> 3, ch = id & 7;
            va[q] = *(const u32x4*)(Ab + r * 512 + kt * 128 + ch * 16);
            vb[q] = *(const u32x4*)(Bb + r * 512 + kt * 128 + ch * 16);
        }
#pragma unroll
        for (int q = 0; q < 4; ++q) {
            int id = q * 256 + tid;
            int r = id >> 3, ch = id & 7;
            *(u32x4*)(sA + SWZ(r, ch * 16)) = va[q];
            *(u32x4*)(sB + SWZ(r, ch * 16)) = vb[q];
        }
        __syncthreads();
#pragma unroll
        for (int kk = 0; kk < 2; ++kk) {
            const int kb = kk * 64 + lk * 16;
            u32x4 af[4], bf[4];
#pragma unroll
            for (int mi = 0; mi < 4; ++mi)
                af[mi] = *(const u32x4*)(sA + SWZ(wm * 64 + mi * 16 + lrow, kb));
#pragma unroll
            for (int ni = 0; ni < 4; ++ni)
                bf[ni] = *(const u32x4*)(sB + SWZ(wn * 64 + ni * 16 + lrow, kb));
#pragma unroll
            for (int mi = 0; mi < 4; ++mi)
#pragma unroll
                for (int ni = 0; ni < 4; ++ni)
                    mfma16(acc[mi][ni], af[mi], bf[ni]);
        }
    }
    asm volatile("s_nop 7\n\ts_nop 7");  // drain MFMA before epilogue VALU reads
}

// stage1: T_u = X[n] * H_u ; store transposed bf16 Tt[j][i].
__global__ void __launch_bounds__(256) stage1(const unsigned short* __restrict__ Xb,
                                              const unsigned short* __restrict__ H,
                                              unsigned short* __restrict__ Tt, int u_off) {
    __shared__ char smem[32768];
    const int ti = blockIdx.x >> 1, tj = blockIdx.x & 1;
    const int n = blockIdx.y, ublk = blockIdx.z, u = u_off + ublk;
    const int i0 = ti * 128, j0 = tj * 128;

    const char* Ab = (const char*)(Xb + (size_t)n * 65536) + i0 * 512;
    const char* Bb = (const char*)(H + (size_t)u * 65536) + j0 * 512;  // H symmetric

    f32x4 acc[4][4];
#pragma unroll
    for (int a = 0; a < 4; ++a)
#pragma unroll
        for (int b = 0; b < 4; ++b) acc[a][b] = (f32x4){0.f, 0.f, 0.f, 0.f};

    gemm_core(Ab, Bb, smem, smem + 16384, acc);

    const int lane = threadIdx.x & 63;
    const int wm = (threadIdx.x >> 7) & 1, wn = (threadIdx.x >> 6) & 1;
    unsigned short* T = Tt + ((size_t)ublk * 64 + n) * 65536;
#pragma unroll
    for (int mi = 0; mi < 4; ++mi) {
        int ig = i0 + wm * 64 + mi * 16 + (lane >> 4) * 4;
#pragma unroll
        for (int ni = 0; ni < 4; ++ni) {
            int jg = j0 + wn * 64 + ni * 16 + (lane & 15);
            u16x4 o = { f2bf(acc[mi][ni].x), f2bf(acc[mi][ni].y),
                        f2bf(acc[mi][ni].z), f2bf(acc[mi][ni].w) };
            *(u16x4*)(T + (size_t)jg * 256 + ig) = o;  // Tt[j][i..i+3]
        }
    }
}

// stage2f: fused stage2 + channel interleave.
// Block owns 128(i) x 32(j) pixel tile of image n; loops u=0..7 with
// acc[8][4] as the Z storage (128 VGPR, fully static indexing), then writes
// out[n,i,j,0..8] with x passthrough — 16 lanes emit 576 contiguous bytes.
__global__ void __launch_bounds__(256) stage2f(const unsigned short* __restrict__ Tt,
                                               const unsigned short* __restrict__ H,
                                               const float* __restrict__ x,
                                               float* __restrict__ out) {
    __shared__ char smem[16384 + 4096];
    char* sA = smem;          // 128 rows x 128B (swizzled)
    char* sB = smem + 16384;  //  32 rows x 128B (swizzled)

    // chunked XCD swizzle (bijective: 1024 % 8 == 0): keeps the 2 i-tiles of a
    // (n, j) pair on one XCD so the shared Tt j-slice is an L2 hit.
    int bid = blockIdx.x;
    int wg  = (bid & 7) * 128 + (bid >> 3);
    int n  = wg >> 4;
    int jt = (wg >> 1) & 7;
    int it = wg & 1;
    const int i0 = it * 128, j0 = jt * 32;

    const int tid  = threadIdx.x;
    const int lane = tid & 63;
    const int wm   = tid >> 7;        // i: 2 x 64
    const int wn   = (tid >> 6) & 1;  // j: 2 x 16
    const int lrow = lane & 15;
    const int lk   = lane >> 4;

    f32x4 acc[8][4];
#pragma unroll
    for (int u = 0; u < 8; ++u)
#pragma unroll
        for (int mi = 0; mi < 4; ++mi) acc[u][mi] = (f32x4){0.f, 0.f, 0.f, 0.f};

    const char* Abase = (const char*)H + i0 * 512;                           // + u*131072
    const char* Bbase = (const char*)Tt + (size_t)n * 131072 + j0 * 512;     // + u*64*131072

#pragma unroll
    for (int u = 0; u < 8; ++u) {
        const char* Ab = Abase + (size_t)u * 131072;
        const char* Bb = Bbase + (size_t)u * 64 * 131072;
#pragma unroll
        for (int kt = 0; kt < 4; ++kt) {
            __syncthreads();
            u32x4 va[4], vb;
#pragma unroll
            for (int q = 0; q < 4; ++q) {
                int id = q * 256 + tid;
                int r = id >> 3, ch = id & 7;
                va[q] = *(const u32x4*)(Ab + r * 512 + kt * 128 + ch * 16);
            }
            {
                int r = tid >> 3, ch = tid & 7;
                vb = *(const u32x4*)(Bb + r * 512 + kt * 128 + ch * 16);
            }
#pragma unroll
            for (int q = 0; q < 4; ++q) {
                int id = q * 256 + tid;
                int r = id >> 3, ch = id & 7;
                *(u32x4*)(sA + SWZ(r, ch * 16)) = va[q];
            }
            {
                int r = tid >> 3, ch = tid & 7;
                *(u32x4*)(sB + SWZ(r, ch * 16)) = vb;
            }
            __syncthreads();
#pragma unroll
            for (int kk = 0; kk < 2; ++kk) {
                const int kb = kk * 64 + lk * 16;
                u32x4 bfr = *(const u32x4*)(sB + SWZ(wn * 16 + lrow, kb));
#pragma unroll
                for (int mi = 0; mi < 4; ++mi) {
                    u32x4 afr = *(const u32x4*)(sA + SWZ(wm * 64 + mi * 16 + lrow, kb));
                    mfma16(acc[u][mi], afr, bfr);
                }
            }
        }
    }
    asm volatile("s_nop 7\n\ts_nop 7");

    // epilogue: all 9 channels per pixel, contiguous 36B pixels
    const int jg = j0 + wn * 16 + lrow;
#pragma unroll
    for (int mi = 0; mi < 4; ++mi) {
        int ig = i0 + wm * 64 + mi * 16 + (lane >> 4) * 4;
#pragma unroll
        for (int r = 0; r < 4; ++r) {
            size_t pix = ((size_t)n * 256 + (ig + r)) * 256 + jg;
            float xv = x[pix];
            float* o = out + pix * 9;
            o[0] = xv;
#pragma unroll
            for (int u = 0; u < 8; ++u) o[1 + u] = acc[u][mi][r];
        }
    }
}

// fallback per-u stage2 with scattered writes (small-ws path only)
__global__ void __launch_bounds__(256) stage2(const unsigned short* __restrict__ Tt,
                                              const unsigned short* __restrict__ H,
                                              float* __restrict__ out, int u) {
    __shared__ char smem[32768];
    const int ti = blockIdx.x >> 1, tj = blockIdx.x & 1;
    const int n = blockIdx.y;
    const int i0 = ti * 128, j0 = tj * 128;

    const char* Ab = (const char*)(H + (size_t)u * 65536) + i0 * 512;
    const char* Bb = (const char*)(Tt + (size_t)n * 65536) + j0 * 512;

    f32x4 acc[4][4];
#pragma unroll
    for (int a = 0; a < 4; ++a)
#pragma unroll
        for (int b = 0; b < 4; ++b) acc[a][b] = (f32x4){0.f, 0.f, 0.f, 0.f};

    gemm_core(Ab, Bb, smem, smem + 16384, acc);

    const int lane = threadIdx.x & 63;
    const int wm = (threadIdx.x >> 7) & 1, wn = (threadIdx.x >> 6) & 1;
#pragma unroll
    for (int mi = 0; mi < 4; ++mi) {
        int ig = i0 + wm * 64 + mi * 16 + (lane >> 4) * 4;
#pragma unroll
        for (int ni = 0; ni < 4; ++ni) {
            int jg = j0 + wn * 64 + ni * 16 + (lane & 15);
            float* o = out + ((((size_t)n * 256 + ig) * 256 + jg) * 9 + 1 + u);
            o[0]    = acc[mi][ni].x;
            o[2304] = acc[mi][ni].y;
            o[4608] = acc[mi][ni].z;
            o[6912] = acc[mi][ni].w;
        }
    }
}

extern "C" void kernel_launch(void* const* d_in, const int* in_sizes, int n_in,
                              void* d_out, int out_size, void* d_ws, size_t ws_size,
                              hipStream_t stream) {
    const float* x = (const float*)d_in[0];
    float* out = (float*)d_out;
    char* ws = (char*)d_ws;

    unsigned short* H  = (unsigned short*)(ws);                // 1,048,576 B
    unsigned short* Xb = (unsigned short*)(ws + 1048576);      // 8,388,608 B
    unsigned short* Tt = (unsigned short*)(ws + 9437184);      // 67,108,864 B (all u)

    const size_t NEED = 76546048ull;  // H + Xb + Tt(all u)

    hbuild<<<2048, 256, 0, stream>>>(H);

    if (ws_size >= NEED) {
        xconv<<<4096, 256, 0, stream>>>(x, Xb, out, 0);
        stage1<<<dim3(4, 64, 8), 256, 0, stream>>>(Xb, H, Tt, 0);
        stage2f<<<1024, 256, 0, stream>>>(Tt, H, x, out);
    } else {
        // minimal-ws fallback: per-u sequencing, Tt holds one u-slice
        xconv<<<4096, 256, 0, stream>>>(x, Xb, out, 1);
        for (int u = 0; u < 8; ++u) {
            stage1<<<dim3(4, 64, 1), 256, 0, stream>>>(Xb, H, Tt, u);
            stage2<<<dim3(4, 64), 256, 0, stream>>>(Tt, H, out, u);
        }
    }
}

// Round 3
// 123.986 us; speedup vs baseline: 1.2879x; 1.2879x over previous
//
#include <hip/hip_runtime.h>

typedef __attribute__((ext_vector_type(4))) float          f32x4;
typedef __attribute__((ext_vector_type(2))) float          f32x2;
typedef __attribute__((ext_vector_type(4))) unsigned int   u32x4;
typedef __attribute__((ext_vector_type(4))) unsigned short u16x4;
typedef __attribute__((ext_vector_type(2))) unsigned short u16x2;

#define PI_F 3.14159265358979f

// round-to-nearest-even fp32 -> bf16
__device__ __forceinline__ unsigned short f2bf(float f) {
    unsigned int x = __float_as_uint(f);
    unsigned int r = ((x >> 16) & 1u) + 0x7fffu;
    return (unsigned short)((x + r) >> 16);
}
__device__ __forceinline__ float bf2f(unsigned short v) {
    return __uint_as_float((unsigned int)v << 16);
}

__device__ __forceinline__ void mfma16(f32x4& c, u32x4 a, u32x4 b) {
    asm volatile("v_mfma_f32_16x16x32_bf16 %0, %1, %2, %0"
                 : "+v"(c) : "v"(a), "v"(b));
}

// ---------------- prep kernels ----------------

// H[u][i][j] = h_u((i-j) mod 256), bf16.
__global__ void hbuild(unsigned short* __restrict__ H) {
    const int US[8] = {5, 22, 39, 57, 74, 92, 109, 127};
    int idx = blockIdx.x * 256 + threadIdx.x;
    int u = idx >> 16;
    int i = (idx >> 8) & 255, j = idx & 255;
    int d = (i - j) & 255;
    int m = 2 * US[u] + 1;
    float h;
    if (d == 0) {
        h = (float)m * (1.0f / 256.0f);
    } else {
        int t = (m * d) & 511;  // sin(pi*m*d/256) has period 512 in (m*d)
        float num = sinf((float)t * (PI_F / 256.0f));
        float den = sinf((float)d * (PI_F / 256.0f));
        h = num / (256.0f * den);
    }
    H[idx] = f2bf(h);
}

// x fp32 -> Xb bf16 (vectorized by 4); optionally write channel 0 of out.
__global__ void xconv(const float* __restrict__ x, unsigned short* __restrict__ Xb,
                      float* __restrict__ out, int write_c0) {
    int idx = blockIdx.x * 256 + threadIdx.x;  // 1,048,576 total
    f32x4 v = ((const f32x4*)x)[idx];
    u16x4 o = { f2bf(v.x), f2bf(v.y), f2bf(v.z), f2bf(v.w) };
    ((u16x4*)Xb)[idx] = o;
    if (write_c0) {
        size_t g = (size_t)idx * 4;
        out[(g + 0) * 9] = v.x;
        out[(g + 1) * 9] = v.y;
        out[(g + 2) * 9] = v.z;
        out[(g + 3) * 9] = v.w;
    }
}

// LDS XOR swizzle: tiles [rows][128 bytes], spread column-slices across banks.
#define SWZ(r, cb) (((unsigned)(r) * 128u) + ((unsigned)(cb) ^ ((((unsigned)(r)) & 7u) << 4)))

// ---------------- 128x128 GEMM core -----------------------------------------
// C[r,c] = sum_k A[r,k] * B[c,k]  (both inputs row-major over their K axis)
__device__ __forceinline__ void gemm_core(const char* __restrict__ Ab,
                                          const char* __restrict__ Bb,
                                          char* sA, char* sB, f32x4 acc[4][4]) {
    const int tid  = threadIdx.x;
    const int lane = tid & 63;
    const int wm   = (tid >> 7) & 1;
    const int wn   = (tid >> 6) & 1;
    const int lrow = lane & 15;
    const int lk   = lane >> 4;

    for (int kt = 0; kt < 4; ++kt) {   // K=256, BK=64
        if (kt) __syncthreads();
        u32x4 va[4], vb[4];
#pragma unroll
        for (int q = 0; q < 4; ++q) {
            int id = q * 256 + tid;
            int r = id >> 3, ch = id & 7;
            va[q] = *(const u32x4*)(Ab + r * 512 + kt * 128 + ch * 16);
            vb[q] = *(const u32x4*)(Bb + r * 512 + kt * 128 + ch * 16);
        }
#pragma unroll
        for (int q = 0; q < 4; ++q) {
            int id = q * 256 + tid;
            int r = id >> 3, ch = id & 7;
            *(u32x4*)(sA + SWZ(r, ch * 16)) = va[q];
            *(u32x4*)(sB + SWZ(r, ch * 16)) = vb[q];
        }
        __syncthreads();
#pragma unroll
        for (int kk = 0; kk < 2; ++kk) {
            const int kb = kk * 64 + lk * 16;
            u32x4 af[4], bf[4];
#pragma unroll
            for (int mi = 0; mi < 4; ++mi)
                af[mi] = *(const u32x4*)(sA + SWZ(wm * 64 + mi * 16 + lrow, kb));
#pragma unroll
            for (int ni = 0; ni < 4; ++ni)
                bf[ni] = *(const u32x4*)(sB + SWZ(wn * 64 + ni * 16 + lrow, kb));
#pragma unroll
            for (int mi = 0; mi < 4; ++mi)
#pragma unroll
                for (int ni = 0; ni < 4; ++ni)
                    mfma16(acc[mi][ni], af[mi], bf[ni]);
        }
    }
    asm volatile("s_nop 7\n\ts_nop 7");  // drain MFMA before epilogue VALU reads
}

// gemmT: O[un][c*256+r] = sum_k A[a][r,k] * B[u][c,k]   (bf16 in/out)
// stage1: A=Xb (per n),      B=H_u, O=Tt  -> Tt[j][i] = (X*H)[i,j]
// stage2: A=Tt (per (u,n)),  B=H_u, O=Zb  -> Zb[i][j] = (H*T)[i,j]
__global__ void __launch_bounds__(256) gemmT(const unsigned short* __restrict__ A,
                                             const unsigned short* __restrict__ B,
                                             unsigned short* __restrict__ O,
                                             int a_per_u, int o_per_u, int u_off) {
    __shared__ char smem[32768];
    const int ti = blockIdx.x >> 1, tj = blockIdx.x & 1;
    const int n = blockIdx.y, u = u_off + blockIdx.z;
    const size_t un = (size_t)(u * 64 + n);

    const char* Ab = (const char*)(A + (a_per_u ? un : (size_t)n) * 65536) + ti * 128 * 512;
    const char* Bb = (const char*)(B + (size_t)u * 65536) + tj * 128 * 512;

    f32x4 acc[4][4];
#pragma unroll
    for (int a = 0; a < 4; ++a)
#pragma unroll
        for (int b = 0; b < 4; ++b) acc[a][b] = (f32x4){0.f, 0.f, 0.f, 0.f};

    gemm_core(Ab, Bb, smem, smem + 16384, acc);

    const int lane = threadIdx.x & 63;
    const int wm = (threadIdx.x >> 7) & 1, wn = (threadIdx.x >> 6) & 1;
    unsigned short* Op = O + (o_per_u ? un : (size_t)n) * 65536;
#pragma unroll
    for (int mi = 0; mi < 4; ++mi) {
        int rg = ti * 128 + wm * 64 + mi * 16 + (lane >> 4) * 4;   // A-row index (contiguous x4)
#pragma unroll
        for (int ni = 0; ni < 4; ++ni) {
            int cg = tj * 128 + wn * 64 + ni * 16 + (lane & 15);   // B-row index
            u16x4 o = { f2bf(acc[mi][ni].x), f2bf(acc[mi][ni].y),
                        f2bf(acc[mi][ni].z), f2bf(acc[mi][ni].w) };
            *(u16x4*)(Op + (size_t)cg * 256 + rg) = o;
        }
    }
}

// pack9: out[p*9+0]=x[p]; out[p*9+1+u]=Zb[u][p].  LDS pixel transpose so every
// global store is a contiguous dwordx4 run (4KB per wave-round).
__global__ void __launch_bounds__(256) pack9(const float* __restrict__ x,
                                             const unsigned short* __restrict__ Zb,
                                             float* __restrict__ out) {
    __shared__ float sl[9216];  // 1024 pixels x 9 ch
    const int t = threadIdx.x;
    const size_t g0 = (size_t)blockIdx.x * 1024;

#pragma unroll
    for (int c = 0; c < 2; ++c) {
        int q = c * 512 + t * 2;          // local pixel pair
        size_t p = g0 + q;
        f32x2 xv = *(const f32x2*)(x + p);
        sl[q * 9]     = xv.x;             // bank = (9q)%32: 2-way max (free)
        sl[(q + 1) * 9] = xv.y;
#pragma unroll
        for (int u = 0; u < 8; ++u) {
            u16x2 z = *(const u16x2*)(Zb + (size_t)u * 4194304 + p);
            sl[q * 9 + 1 + u]       = bf2f(z.x);
            sl[(q + 1) * 9 + 1 + u] = bf2f(z.y);
        }
    }
    __syncthreads();
    float* ob = out + g0 * 9;
#pragma unroll
    for (int r = 0; r < 9; ++r) {
        int d = r * 1024 + t * 4;
        *(f32x4*)(ob + d) = *(const f32x4*)&sl[d];
    }
}

// ---------------- round-2 fallback kernels (kept verbatim) -------------------
__global__ void __launch_bounds__(256) stage2f(const unsigned short* __restrict__ Tt,
                                               const unsigned short* __restrict__ H,
                                               const float* __restrict__ x,
                                               float* __restrict__ out) {
    __shared__ char smem[16384 + 4096];
    char* sA = smem;
    char* sB = smem + 16384;
    int bid = blockIdx.x;
    int wg  = (bid & 7) * 128 + (bid >> 3);
    int n  = wg >> 4;
    int jt = (wg >> 1) & 7;
    int it = wg & 1;
    const int i0 = it * 128, j0 = jt * 32;
    const int tid  = threadIdx.x;
    const int lane = tid & 63;
    const int wm   = tid >> 7;
    const int wn   = (tid >> 6) & 1;
    const int lrow = lane & 15;
    const int lk   = lane >> 4;

    f32x4 acc[8][4];
#pragma unroll
    for (int u = 0; u < 8; ++u)
#pragma unroll
        for (int mi = 0; mi < 4; ++mi) acc[u][mi] = (f32x4){0.f, 0.f, 0.f, 0.f};

    const char* Abase = (const char*)H + i0 * 512;
    const char* Bbase = (const char*)Tt + (size_t)n * 131072 + j0 * 512;

#pragma unroll
    for (int u = 0; u < 8; ++u) {
        const char* Ab = Abase + (size_t)u * 131072;
        const char* Bb = Bbase + (size_t)u * 64 * 131072;
#pragma unroll
        for (int kt = 0; kt < 4; ++kt) {
            __syncthreads();
            u32x4 va[4], vb;
#pragma unroll
            for (int q = 0; q < 4; ++q) {
                int id = q * 256 + tid;
                int r = id >> 3, ch = id & 7;
                va[q] = *(const u32x4*)(Ab + r * 512 + kt * 128 + ch * 16);
            }
            {
                int r = tid >> 3, ch = tid & 7;
                vb = *(const u32x4*)(Bb + r * 512 + kt * 128 + ch * 16);
            }
#pragma unroll
            for (int q = 0; q < 4; ++q) {
                int id = q * 256 + tid;
                int r = id >> 3, ch = id & 7;
                *(u32x4*)(sA + SWZ(r, ch * 16)) = va[q];
            }
            {
                int r = tid >> 3, ch = tid & 7;
                *(u32x4*)(sB + SWZ(r, ch * 16)) = vb;
            }
            __syncthreads();
#pragma unroll
            for (int kk = 0; kk < 2; ++kk) {
                const int kb = kk * 64 + lk * 16;
                u32x4 bfr = *(const u32x4*)(sB + SWZ(wn * 16 + lrow, kb));
#pragma unroll
                for (int mi = 0; mi < 4; ++mi) {
                    u32x4 afr = *(const u32x4*)(sA + SWZ(wm * 64 + mi * 16 + lrow, kb));
                    mfma16(acc[u][mi], afr, bfr);
                }
            }
        }
    }
    asm volatile("s_nop 7\n\ts_nop 7");

    const int jg = j0 + wn * 16 + lrow;
#pragma unroll
    for (int mi = 0; mi < 4; ++mi) {
        int ig = i0 + wm * 64 + mi * 16 + (lane >> 4) * 4;
#pragma unroll
        for (int r = 0; r < 4; ++r) {
            size_t pix = ((size_t)n * 256 + (ig + r)) * 256 + jg;
            float xv = x[pix];
            float* o = out + pix * 9;
            o[0] = xv;
#pragma unroll
            for (int u = 0; u < 8; ++u) o[1 + u] = acc[u][mi][r];
        }
    }
}

__global__ void __launch_bounds__(256) stage2(const unsigned short* __restrict__ Tt,
                                              const unsigned short* __restrict__ H,
                                              float* __restrict__ out, int u) {
    __shared__ char smem[32768];
    const int ti = blockIdx.x >> 1, tj = blockIdx.x & 1;
    const int n = blockIdx.y;
    const int i0 = ti * 128, j0 = tj * 128;

    const char* Ab = (const char*)(H + (size_t)u * 65536) + i0 * 512;
    const char* Bb = (const char*)(Tt + (size_t)n * 65536) + j0 * 512;

    f32x4 acc[4][4];
#pragma unroll
    for (int a = 0; a < 4; ++a)
#pragma unroll
        for (int b = 0; b < 4; ++b) acc[a][b] = (f32x4){0.f, 0.f, 0.f, 0.f};

    gemm_core(Ab, Bb, smem, smem + 16384, acc);

    const int lane = threadIdx.x & 63;
    const int wm = (threadIdx.x >> 7) & 1, wn = (threadIdx.x >> 6) & 1;
#pragma unroll
    for (int mi = 0; mi < 4; ++mi) {
        int ig = i0 + wm * 64 + mi * 16 + (lane >> 4) * 4;
#pragma unroll
        for (int ni = 0; ni < 4; ++ni) {
            int jg = j0 + wn * 64 + ni * 16 + (lane & 15);
            float* o = out + ((((size_t)n * 256 + ig) * 256 + jg) * 9 + 1 + u);
            o[0]    = acc[mi][ni].x;
            o[2304] = acc[mi][ni].y;
            o[4608] = acc[mi][ni].z;
            o[6912] = acc[mi][ni].w;
        }
    }
}

extern "C" void kernel_launch(void* const* d_in, const int* in_sizes, int n_in,
                              void* d_out, int out_size, void* d_ws, size_t ws_size,
                              hipStream_t stream) {
    const float* x = (const float*)d_in[0];
    float* out = (float*)d_out;
    char* ws = (char*)d_ws;

    unsigned short* H  = (unsigned short*)(ws);                // 1 MB
    unsigned short* Xb = (unsigned short*)(ws + 1048576);      // 8 MB
    unsigned short* Tt = (unsigned short*)(ws + 9437184);      // 64 MB (all u)
    unsigned short* Zb = (unsigned short*)(ws + 76546048);     // 64 MB (all u)

    const size_t NEED_FULL = 143654912ull;  // H + Xb + Tt + Zb
    const size_t NEED_MID  = 76546048ull;   // H + Xb + Tt

    hbuild<<<2048, 256, 0, stream>>>(H);

    if (ws_size >= NEED_FULL) {
        xconv<<<4096, 256, 0, stream>>>(x, Xb, out, 0);
        gemmT<<<dim3(4, 64, 8), 256, 0, stream>>>(Xb, H, Tt, 0, 1, 0);  // stage1
        gemmT<<<dim3(4, 64, 8), 256, 0, stream>>>(Tt, H, Zb, 1, 1, 0);  // stage2
        pack9<<<4096, 256, 0, stream>>>(x, Zb, out);
    } else if (ws_size >= NEED_MID) {
        xconv<<<4096, 256, 0, stream>>>(x, Xb, out, 0);
        gemmT<<<dim3(4, 64, 8), 256, 0, stream>>>(Xb, H, Tt, 0, 1, 0);
        stage2f<<<1024, 256, 0, stream>>>(Tt, H, x, out);
    } else {
        xconv<<<4096, 256, 0, stream>>>(x, Xb, out, 1);
        for (int u = 0; u < 8; ++u) {
            gemmT<<<dim3(4, 64, 1), 256, 0, stream>>>(Xb, H, Tt, 0, 0, u);
            stage2<<<dim3(4, 64), 256, 0, stream>>>(Tt, H, out, u);
        }
    }
}

// Round 4
// 117.998 us; speedup vs baseline: 1.3532x; 1.0507x over previous
//
#include <hip/hip_runtime.h>

typedef __attribute__((ext_vector_type(4))) float          f32x4;
typedef __attribute__((ext_vector_type(2))) float          f32x2;
typedef __attribute__((ext_vector_type(4))) unsigned int   u32x4;
typedef __attribute__((ext_vector_type(4))) unsigned short u16x4;
typedef __attribute__((ext_vector_type(2))) unsigned short u16x2;

typedef const unsigned int __attribute__((address_space(1)))* gas_ptr;
typedef unsigned int __attribute__((address_space(3)))*       las_ptr;

#define PI_F 3.14159265358979f

// round-to-nearest-even fp32 -> bf16
__device__ __forceinline__ unsigned short f2bf(float f) {
    unsigned int x = __float_as_uint(f);
    unsigned int r = ((x >> 16) & 1u) + 0x7fffu;
    return (unsigned short)((x + r) >> 16);
}
__device__ __forceinline__ float bf2f(unsigned short v) {
    return __uint_as_float((unsigned int)v << 16);
}

__device__ __forceinline__ void mfma16(f32x4& c, u32x4 a, u32x4 b) {
    asm volatile("v_mfma_f32_16x16x32_bf16 %0, %1, %2, %0"
                 : "+v"(c) : "v"(a), "v"(b));
}

// async global->LDS, 16B per lane; LDS dest is wave-uniform base + lane*16.
__device__ __forceinline__ void gload16(const void* g, void* l) {
    __builtin_amdgcn_global_load_lds((gas_ptr)g, (las_ptr)l, 16, 0, 0);
}

// ---------------- pre-swizzled global tile format ---------------------------
// All GEMM-facing bf16 matrices (H, Xb, Tt) are 256x256, row stride 512B.
// Within each 64-element K-quarter of a row r, element k is STORED at
// k ^ ((r&7)<<3).  A linear global_load_lds of a row-quarter then lands in
// LDS exactly where the swizzled fragment reads (SWZ below) expect it.
#define SWZ(r, cb) (((unsigned)(r) * 128u) + ((unsigned)(cb) ^ ((((unsigned)(r)) & 7u) << 4)))

// H[u][i][j_s] = h_u(i - j_l),  j_l = j_s ^ ((i&7)<<3)   (pre-swizzled)
__global__ void hbuild(unsigned short* __restrict__ H) {
    const int US[8] = {5, 22, 39, 57, 74, 92, 109, 127};
    int idx = blockIdx.x * 256 + threadIdx.x;
    int u = idx >> 16;
    int i = (idx >> 8) & 255, js = idx & 255;
    int jl = js ^ ((i & 7) << 3);
    int d = (i - jl) & 255;
    int m = 2 * US[u] + 1;
    float h;
    if (d == 0) {
        h = (float)m * (1.0f / 256.0f);
    } else {
        int t = (m * d) & 511;  // sin(pi*m*d/256) has period 512 in (m*d)
        float num = sinf((float)t * (PI_F / 256.0f));
        float den = sinf((float)d * (PI_F / 256.0f));
        h = num / (256.0f * den);
    }
    H[idx] = f2bf(h);
}

// x fp32 -> Xb bf16 pre-swizzled; optionally write channel 0 of out (fallback).
__global__ void xconv(const float* __restrict__ x, unsigned short* __restrict__ Xb,
                      float* __restrict__ out, int write_c0) {
    int idx = blockIdx.x * 256 + threadIdx.x;   // u16x4 units; 1,048,576 total
    f32x4 v = ((const f32x4*)x)[idx];
    u16x4 o = { f2bf(v.x), f2bf(v.y), f2bf(v.z), f2bf(v.w) };
    int n = idx >> 14;
    int t = idx & 16383;
    int i = t >> 6;
    int jl = (t & 63) * 4;
    int js = jl ^ ((i & 7) << 3);               // stays 4-aligned (XOR on bits 3-5)
    *(u16x4*)(Xb + (size_t)n * 65536 + i * 256 + js) = o;
    if (write_c0) {
        size_t g = (size_t)idx * 4;
        out[(g + 0) * 9] = v.x;
        out[(g + 1) * 9] = v.y;
        out[(g + 2) * 9] = v.z;
        out[(g + 3) * 9] = v.w;
    }
}

// ---------------- GEMM: C[r,c] = sum_k A[r,k]*B[c,k], 128x128 tile ----------
// A,B pre-swizzled bf16 256x256.  mode: 0 = bf16 linear out (Zb planes),
// 1 = bf16 pre-swizzled out (Tt), 2 = fp32 direct scatter to out (fallback).
__global__ void __launch_bounds__(256) gemmT(const unsigned short* __restrict__ A,
                                             const unsigned short* __restrict__ B,
                                             unsigned short* __restrict__ O,
                                             float* __restrict__ fOut,
                                             int a_per_u, int o_per_u, int u_off, int mode) {
    __shared__ char smem[32768];
    char* sA = smem;
    char* sB = smem + 16384;

    const int ti = blockIdx.x >> 1, tj = blockIdx.x & 1;
    const int n = blockIdx.y, u = u_off + blockIdx.z;
    const size_t un = (size_t)(u * 64 + n);

    const char* Ab = (const char*)(A + (a_per_u ? un : (size_t)n) * 65536) + ti * 128 * 512;
    const char* Bb = (const char*)(B + (size_t)u * 65536) + tj * 128 * 512;

    const int tid  = threadIdx.x;
    const int lane = tid & 63;
    const int w    = tid >> 6;
    const int wm   = (tid >> 7) & 1;
    const int wn   = (tid >> 6) & 1;
    const int lrow = lane & 15;
    const int lk   = lane >> 4;

    // staging addresses: instr q covers tile rows (w*4+q)*8 .. +7, lane -> (row, chunk)
    const int srow = lane >> 3, sch = lane & 7;
    const char* gA[4];
    const char* gB[4];
#pragma unroll
    for (int q = 0; q < 4; ++q) {
        int r = (w * 4 + q) * 8 + srow;
        gA[q] = Ab + r * 512 + sch * 16;
        gB[q] = Bb + r * 512 + sch * 16;
    }

    f32x4 acc[4][4];
#pragma unroll
    for (int a = 0; a < 4; ++a)
#pragma unroll
        for (int b = 0; b < 4; ++b) acc[a][b] = (f32x4){0.f, 0.f, 0.f, 0.f};

    for (int kt = 0; kt < 4; ++kt) {   // K=256, BK=64
        if (kt) __syncthreads();       // prior fragment reads done before overwrite
#pragma unroll
        for (int q = 0; q < 4; ++q) {
            gload16(gA[q] + kt * 128, sA + (w * 4 + q) * 1024);
            gload16(gB[q] + kt * 128, sB + (w * 4 + q) * 1024);
        }
        __syncthreads();               // compiler drains vmcnt(0) before barrier
#pragma unroll
        for (int kk = 0; kk < 2; ++kk) {
            const int kb = kk * 64 + lk * 16;
            u32x4 af[4], bf[4];
#pragma unroll
            for (int mi = 0; mi < 4; ++mi)
                af[mi] = *(const u32x4*)(sA + SWZ(wm * 64 + mi * 16 + lrow, kb));
#pragma unroll
            for (int ni = 0; ni < 4; ++ni)
                bf[ni] = *(const u32x4*)(sB + SWZ(wn * 64 + ni * 16 + lrow, kb));
#pragma unroll
            for (int mi = 0; mi < 4; ++mi)
#pragma unroll
                for (int ni = 0; ni < 4; ++ni)
                    mfma16(acc[mi][ni], af[mi], bf[ni]);
        }
    }
    asm volatile("s_nop 7\n\ts_nop 7");  // drain MFMA before epilogue VALU reads

    unsigned short* Op = O ? O + (o_per_u ? un : (size_t)n) * 65536 : nullptr;
#pragma unroll
    for (int mi = 0; mi < 4; ++mi) {
        int rg = ti * 128 + wm * 64 + mi * 16 + (lane >> 4) * 4;   // A-row (4 consecutive)
#pragma unroll
        for (int ni = 0; ni < 4; ++ni) {
            int cg = tj * 128 + wn * 64 + ni * 16 + lrow;          // B-row
            if (mode == 2) {
                // stage2 fallback: A=Tt (r=j), B=H (c=i): C[j,i]=Z[i,j]
                float* o = fOut + (((size_t)n * 256 + cg) * 256 + rg) * 9 + 1 + u;
                o[0]  = acc[mi][ni].x;
                o[9]  = acc[mi][ni].y;
                o[18] = acc[mi][ni].z;
                o[27] = acc[mi][ni].w;
            } else {
                u16x4 o = { f2bf(acc[mi][ni].x), f2bf(acc[mi][ni].y),
                            f2bf(acc[mi][ni].z), f2bf(acc[mi][ni].w) };
                int rs = (mode == 1) ? (rg ^ ((cg & 7) << 3)) : rg;  // pre-swizzle Tt
                *(u16x4*)(Op + (size_t)cg * 256 + rs) = o;
            }
        }
    }
}

// pack9: out[p*9+0]=x[p]; out[p*9+1+u]=Zb[u][p].  LDS pixel transpose so every
// global store is a contiguous dwordx4 run.
__global__ void __launch_bounds__(256) pack9(const float* __restrict__ x,
                                             const unsigned short* __restrict__ Zb,
                                             float* __restrict__ out) {
    __shared__ float sl[9216];  // 1024 pixels x 9 ch
    const int t = threadIdx.x;
    const size_t g0 = (size_t)blockIdx.x * 1024;

#pragma unroll
    for (int c = 0; c < 2; ++c) {
        int q = c * 512 + t * 2;
        size_t p = g0 + q;
        f32x2 xv = *(const f32x2*)(x + p);
        sl[q * 9]       = xv.x;
        sl[(q + 1) * 9] = xv.y;
#pragma unroll
        for (int u = 0; u < 8; ++u) {
            u16x2 z = *(const u16x2*)(Zb + (size_t)u * 4194304 + p);
            sl[q * 9 + 1 + u]       = bf2f(z.x);
            sl[(q + 1) * 9 + 1 + u] = bf2f(z.y);
        }
    }
    __syncthreads();
    float* ob = out + g0 * 9;
#pragma unroll
    for (int r = 0; r < 9; ++r) {
        int d = r * 1024 + t * 4;
        *(f32x4*)(ob + d) = *(const f32x4*)&sl[d];
    }
}

extern "C" void kernel_launch(void* const* d_in, const int* in_sizes, int n_in,
                              void* d_out, int out_size, void* d_ws, size_t ws_size,
                              hipStream_t stream) {
    const float* x = (const float*)d_in[0];
    float* out = (float*)d_out;
    char* ws = (char*)d_ws;

    unsigned short* H  = (unsigned short*)(ws);                // 1 MB
    unsigned short* Xb = (unsigned short*)(ws + 1048576);      // 8 MB
    unsigned short* Tt = (unsigned short*)(ws + 9437184);      // 64 MB (all u)
    unsigned short* Zb = (unsigned short*)(ws + 76546048);     // 64 MB (all u)

    const size_t NEED_FULL = 143654912ull;  // H + Xb + Tt + Zb
    const size_t NEED_MIN  = 17825792ull;   // H + Xb + Tt one-u slice

    hbuild<<<2048, 256, 0, stream>>>(H);

    if (ws_size >= NEED_FULL) {
        xconv<<<4096, 256, 0, stream>>>(x, Xb, out, 0);
        // stage1: A=Xb (per n), B=H_u -> Tt[un] pre-swizzled
        gemmT<<<dim3(4, 64, 8), 256, 0, stream>>>(Xb, H, Tt, nullptr, 0, 1, 0, 1);
        // stage2: A=Tt (per un), B=H_u -> Zb[un] linear
        gemmT<<<dim3(4, 64, 8), 256, 0, stream>>>(Tt, H, Zb, nullptr, 1, 1, 0, 0);
        pack9<<<4096, 256, 0, stream>>>(x, Zb, out);
    } else {
        // minimal-ws fallback: per-u sequencing, Tt holds one u-slice,
        // stage2 scatters fp32 directly into the channel-interleaved out.
        xconv<<<4096, 256, 0, stream>>>(x, Xb, out, 1);
        for (int u = 0; u < 8; ++u) {
            gemmT<<<dim3(4, 64, 1), 256, 0, stream>>>(Xb, H, Tt, nullptr, 0, 0, u, 1);
            gemmT<<<dim3(4, 64, 1), 256, 0, stream>>>(Tt, H, nullptr, out, 0, 0, u, 2);
        }
    }
}

// Round 5
// 102.132 us; speedup vs baseline: 1.5635x; 1.1554x over previous
//
#include <hip/hip_runtime.h>

typedef __attribute__((ext_vector_type(4))) float          f32x4;
typedef __attribute__((ext_vector_type(2))) float          f32x2;
typedef __attribute__((ext_vector_type(4))) unsigned int   u32x4;
typedef __attribute__((ext_vector_type(4))) unsigned short u16x4;
typedef __attribute__((ext_vector_type(2))) unsigned short u16x2;

typedef const unsigned int __attribute__((address_space(1)))* gas_ptr;
typedef unsigned int __attribute__((address_space(3)))*       las_ptr;

#define PI_F 3.14159265358979f

__device__ __forceinline__ unsigned short f2bf(float f) {
    unsigned int x = __float_as_uint(f);
    unsigned int r = ((x >> 16) & 1u) + 0x7fffu;
    return (unsigned short)((x + r) >> 16);
}
__device__ __forceinline__ float bf2f(unsigned short v) {
    return __uint_as_float((unsigned int)v << 16);
}
__device__ __forceinline__ void mfma16(f32x4& c, u32x4 a, u32x4 b) {
    asm volatile("v_mfma_f32_16x16x32_bf16 %0, %1, %2, %0"
                 : "+v"(c) : "v"(a), "v"(b));
}
__device__ __forceinline__ void gload16(const void* g, void* l) {
    __builtin_amdgcn_global_load_lds((gas_ptr)g, (las_ptr)l, 16, 0, 0);
}

// Pre-swizzled global format (verified round 4): 256x256 bf16, row stride 512B;
// within each 64-elem K-quarter of row r, element k stored at k ^ ((r&7)<<3).
// Linear gload_lds of a row-quarter lands where swizzled fragment reads expect.
#define SWZ(r, cb) (((unsigned)(r) * 128u) + ((unsigned)(cb) ^ ((((unsigned)(r)) & 7u) << 4)))

// prep: fused hbuild (blocks 0..2047) + xconv (blocks 2048..6143).
__global__ void prep(const float* __restrict__ x, unsigned short* __restrict__ H,
                     unsigned short* __restrict__ Xb, float* __restrict__ out,
                     int write_c0) {
    int b = blockIdx.x;
    if (b < 2048) {
        const int US[8] = {5, 22, 39, 57, 74, 92, 109, 127};
        int idx = b * 256 + threadIdx.x;
        int u = idx >> 16;
        int i = (idx >> 8) & 255, js = idx & 255;
        int jl = js ^ ((i & 7) << 3);
        int d = (i - jl) & 255;
        int m = 2 * US[u] + 1;
        float h;
        if (d == 0) {
            h = (float)m * (1.0f / 256.0f);
        } else {
            int t = (m * d) & 511;
            float num = sinf((float)t * (PI_F / 256.0f));
            float den = sinf((float)d * (PI_F / 256.0f));
            h = num / (256.0f * den);
        }
        H[idx] = f2bf(h);
    } else {
        int idx = (b - 2048) * 256 + threadIdx.x;   // u16x4 units
        f32x4 v = ((const f32x4*)x)[idx];
        u16x4 o = { f2bf(v.x), f2bf(v.y), f2bf(v.z), f2bf(v.w) };
        int n = idx >> 14;
        int t = idx & 16383;
        int i = t >> 6;
        int jlin = (t & 63) * 4;
        int js = jlin ^ ((i & 7) << 3);
        *(u16x4*)(Xb + (size_t)n * 65536 + i * 256 + js) = o;
        if (write_c0) {
            size_t g = (size_t)idx * 4;
            out[(g + 0) * 9] = v.x;
            out[(g + 1) * 9] = v.y;
            out[(g + 2) * 9] = v.z;
            out[(g + 3) * 9] = v.w;
        }
    }
}

// stage12: fused T_u = X*H_u (phase A, into LDS) and Z_u = H_u*T_u (phase B).
// Block = (n, u, j-half). LDS: 32KB stage (X / H-full) + 16KB H-half + 64KB T^T.
// Phase A: C[i,jl] = sum_k X[i,k] H[jg,k]  -> T^T[jl][i] in LDS (swizzled).
// Phase B: C[jl,i] = sum_k T^T[jl,k] H[i,k] = Z[i,jg] -> Zb linear (or fp32 scatter).
__global__ void __launch_bounds__(512) stage12(const unsigned short* __restrict__ Xb,
                                               const unsigned short* __restrict__ H,
                                               unsigned short* __restrict__ Zb,
                                               float* __restrict__ fOut,
                                               int mode, int u_fixed) {
    extern __shared__ char smem[];
    char* sStage = smem;            // 32KB: 256 rows x 128B
    char* sHalf  = smem + 32768;    // 16KB: 128 rows x 128B
    char* sT     = smem + 49152;    // 64KB: 128 rows x 512B (T^T, swizzled)

    int n, u, jh;
    if (u_fixed >= 0) {
        n = blockIdx.x >> 1; jh = blockIdx.x & 1; u = u_fixed;
    } else {
        int swz = (blockIdx.x & 7) * 128 + (blockIdx.x >> 3);  // XCD-chunked, bijective
        n = swz >> 4; u = (swz >> 1) & 7; jh = swz & 1;
    }

    const char* Xn = (const char*)(Xb + (size_t)n * 65536);
    const char* Hu = (const char*)(H + (size_t)u * 65536);

    const int tid  = threadIdx.x;
    const int lane = tid & 63;
    const int w    = tid >> 6;        // 0..7
    const int lrow = lane & 15;
    const int lk   = lane >> 4;
    const int srow = lane >> 3, sch = lane & 7;

    f32x4 acc[4][4];
#pragma unroll
    for (int a = 0; a < 4; ++a)
#pragma unroll
        for (int b = 0; b < 4; ++b) acc[a][b] = (f32x4){0.f, 0.f, 0.f, 0.f};

    // ---------------- phase A: T^T[jl][i] ----------------
    const int wiA = w >> 1, wjA = w & 1;   // 4 i-tiles x 2 j-tiles of 64
    for (int kt = 0; kt < 4; ++kt) {
        if (kt) __syncthreads();
#pragma unroll
        for (int q = 0; q < 4; ++q) {      // X: rows 0..255
            int r = (w * 4 + q) * 8 + srow;
            gload16(Xn + r * 512 + kt * 128 + sch * 16, sStage + (w * 4 + q) * 1024);
        }
#pragma unroll
        for (int q = 0; q < 2; ++q) {      // H rows jh*128 .. +127
            int r = jh * 128 + (w * 2 + q) * 8 + srow;
            gload16(Hu + r * 512 + kt * 128 + sch * 16, sHalf + (w * 2 + q) * 1024);
        }
        __syncthreads();
#pragma unroll
        for (int kk = 0; kk < 2; ++kk) {
            const int kb = kk * 64 + lk * 16;
            u32x4 af[4], bf[4];
#pragma unroll
            for (int mi = 0; mi < 4; ++mi)
                af[mi] = *(const u32x4*)(sStage + SWZ(wiA * 64 + mi * 16 + lrow, kb));
#pragma unroll
            for (int ni = 0; ni < 4; ++ni)
                bf[ni] = *(const u32x4*)(sHalf + SWZ(wjA * 64 + ni * 16 + lrow, kb));
#pragma unroll
            for (int mi = 0; mi < 4; ++mi)
#pragma unroll
                for (int ni = 0; ni < 4; ++ni)
                    mfma16(acc[mi][ni], af[mi], bf[ni]);
        }
    }
    asm volatile("s_nop 7\n\ts_nop 7");
    // epilogue A -> LDS T^T (bf16, swizzled: row jl stride 512B, byte 2i ^ ((jl&7)<<4))
#pragma unroll
    for (int mi = 0; mi < 4; ++mi) {
        int i4 = wiA * 64 + mi * 16 + (lane >> 4) * 4;
#pragma unroll
        for (int ni = 0; ni < 4; ++ni) {
            int jl = wjA * 64 + ni * 16 + lrow;
            u16x4 o = { f2bf(acc[mi][ni].x), f2bf(acc[mi][ni].y),
                        f2bf(acc[mi][ni].z), f2bf(acc[mi][ni].w) };
            *(u16x4*)(sT + jl * 512 + ((2 * i4) ^ ((jl & 7) << 4))) = o;
        }
    }
    __syncthreads();   // T^T visible; sStage free for reuse

    // ---------------- phase B: Z[i, jg] ----------------
#pragma unroll
    for (int a = 0; a < 4; ++a)
#pragma unroll
        for (int b = 0; b < 4; ++b) acc[a][b] = (f32x4){0.f, 0.f, 0.f, 0.f};

    const int wrB = w & 1, wcB = w >> 1;   // 2 jl-tiles x 4 i-tiles of 64
    for (int kt = 0; kt < 4; ++kt) {
        if (kt) __syncthreads();
#pragma unroll
        for (int q = 0; q < 4; ++q) {      // H rows 0..255 -> sStage
            int r = (w * 4 + q) * 8 + srow;
            gload16(Hu + r * 512 + kt * 128 + sch * 16, sStage + (w * 4 + q) * 1024);
        }
        __syncthreads();
#pragma unroll
        for (int kk = 0; kk < 2; ++kk) {
            const int kb  = kk * 64 + lk * 16;
            const int kbT = kt * 128 + kb;
            u32x4 af[4], bf[4];
#pragma unroll
            for (int mi = 0; mi < 4; ++mi) {
                int r = wrB * 64 + mi * 16 + lrow;
                af[mi] = *(const u32x4*)(sT + r * 512 + (kbT ^ ((r & 7) << 4)));
            }
#pragma unroll
            for (int ni = 0; ni < 4; ++ni)
                bf[ni] = *(const u32x4*)(sStage + SWZ(wcB * 64 + ni * 16 + lrow, kb));
#pragma unroll
            for (int mi = 0; mi < 4; ++mi)
#pragma unroll
                for (int ni = 0; ni < 4; ++ni)
                    mfma16(acc[mi][ni], af[mi], bf[ni]);
        }
    }
    asm volatile("s_nop 7\n\ts_nop 7");

    if (mode == 0) {
        unsigned short* Op = Zb + ((size_t)(u * 64 + n)) * 65536 + jh * 128;
#pragma unroll
        for (int mi = 0; mi < 4; ++mi) {
            int r4 = wrB * 64 + mi * 16 + (lane >> 4) * 4;   // jl (4 consecutive)
#pragma unroll
            for (int ni = 0; ni < 4; ++ni) {
                int c = wcB * 64 + ni * 16 + lrow;           // i
                u16x4 o = { f2bf(acc[mi][ni].x), f2bf(acc[mi][ni].y),
                            f2bf(acc[mi][ni].z), f2bf(acc[mi][ni].w) };
                *(u16x4*)(Op + (size_t)c * 256 + r4) = o;
            }
        }
    } else {
#pragma unroll
        for (int mi = 0; mi < 4; ++mi) {
            int r4 = wrB * 64 + mi * 16 + (lane >> 4) * 4;
#pragma unroll
            for (int ni = 0; ni < 4; ++ni) {
                int c = wcB * 64 + ni * 16 + lrow;
                float* o = fOut + (((size_t)n * 256 + c) * 256 + jh * 128 + r4) * 9 + 1 + u;
                o[0]  = acc[mi][ni].x;
                o[9]  = acc[mi][ni].y;
                o[18] = acc[mi][ni].z;
                o[27] = acc[mi][ni].w;
            }
        }
    }
}

// pack9: out[p*9+0]=x[p]; out[p*9+1+u]=Zb[u][p]; contiguous dwordx4 stores.
__global__ void __launch_bounds__(256) pack9(const float* __restrict__ x,
                                             const unsigned short* __restrict__ Zb,
                                             float* __restrict__ out) {
    __shared__ float sl[9216];
    const int t = threadIdx.x;
    const size_t g0 = (size_t)blockIdx.x * 1024;

#pragma unroll
    for (int c = 0; c < 2; ++c) {
        int q = c * 512 + t * 2;
        size_t p = g0 + q;
        f32x2 xv = *(const f32x2*)(x + p);
        sl[q * 9]       = xv.x;
        sl[(q + 1) * 9] = xv.y;
#pragma unroll
        for (int u = 0; u < 8; ++u) {
            u16x2 z = *(const u16x2*)(Zb + (size_t)u * 4194304 + p);
            sl[q * 9 + 1 + u]       = bf2f(z.x);
            sl[(q + 1) * 9 + 1 + u] = bf2f(z.y);
        }
    }
    __syncthreads();
    float* ob = out + g0 * 9;
#pragma unroll
    for (int r = 0; r < 9; ++r) {
        int d = r * 1024 + t * 4;
        *(f32x4*)(ob + d) = *(const f32x4*)&sl[d];
    }
}

extern "C" void kernel_launch(void* const* d_in, const int* in_sizes, int n_in,
                              void* d_out, int out_size, void* d_ws, size_t ws_size,
                              hipStream_t stream) {
    const float* x = (const float*)d_in[0];
    float* out = (float*)d_out;
    char* ws = (char*)d_ws;

    unsigned short* H  = (unsigned short*)(ws);                // 1 MB
    unsigned short* Xb = (unsigned short*)(ws + 1048576);      // 8 MB
    unsigned short* Zb = (unsigned short*)(ws + 9437184);      // 64 MB

    const size_t NEED_FULL = 76546048ull;   // H + Xb + Zb
    const size_t LDS_BYTES = 114688;        // 112 KB dynamic

    if (ws_size >= NEED_FULL) {
        prep<<<6144, 256, 0, stream>>>(x, H, Xb, out, 0);
        stage12<<<1024, 512, LDS_BYTES, stream>>>(Xb, H, Zb, nullptr, 0, -1);
        pack9<<<4096, 256, 0, stream>>>(x, Zb, out);
    } else {
        // minimal-ws fallback (9 MB): per-u, fp32 scatter epilogue
        prep<<<6144, 256, 0, stream>>>(x, H, Xb, out, 1);
        for (int u = 0; u < 8; ++u)
            stage12<<<128, 512, LDS_BYTES, stream>>>(Xb, H, nullptr, out, 1, u);
    }
}

// Round 7
// 96.541 us; speedup vs baseline: 1.6540x; 1.0579x over previous
//
#include <hip/hip_runtime.h>

typedef __attribute__((ext_vector_type(4))) float          f32x4;
typedef __attribute__((ext_vector_type(2))) float          f32x2;
typedef __attribute__((ext_vector_type(4))) unsigned int   u32x4;
typedef __attribute__((ext_vector_type(4))) unsigned short u16x4;
typedef __attribute__((ext_vector_type(2))) unsigned short u16x2;

typedef const unsigned int __attribute__((address_space(1)))* gas_ptr;
typedef unsigned int __attribute__((address_space(3)))*       las_ptr;

#define PI_F 3.14159265358979f

__device__ __forceinline__ unsigned short f2bf(float f) {
    unsigned int x = __float_as_uint(f);
    unsigned int r = ((x >> 16) & 1u) + 0x7fffu;
    return (unsigned short)((x + r) >> 16);
}
__device__ __forceinline__ float bf2f(unsigned short v) {
    return __uint_as_float((unsigned int)v << 16);
}
__device__ __forceinline__ void mfma16(f32x4& c, u32x4 a, u32x4 b) {
    asm volatile("v_mfma_f32_16x16x32_bf16 %0, %1, %2, %0"
                 : "+v"(c) : "v"(a), "v"(b));
}
__device__ __forceinline__ void gload16(const void* g, void* l) {
    __builtin_amdgcn_global_load_lds((gas_ptr)g, (las_ptr)l, 16, 0, 0);
}

// Pre-swizzled global format (verified r4/r5): 256x256 bf16, row stride 512B;
// within each 64-elem K-quarter of row r, element k stored at k ^ ((r&7)<<3).
#define SWZ(r, cb) (((unsigned)(r) * 128u) + ((unsigned)(cb) ^ ((((unsigned)(r)) & 7u) << 4)))

// prep: fused hbuild (blocks 0..2047) + xconv (blocks 2048..6143).
__global__ void prep(const float* __restrict__ x, unsigned short* __restrict__ H,
                     unsigned short* __restrict__ Xb, float* __restrict__ out,
                     int write_c0) {
    int b = blockIdx.x;
    if (b < 2048) {
        const int US[8] = {5, 22, 39, 57, 74, 92, 109, 127};
        int idx = b * 256 + threadIdx.x;
        int u = idx >> 16;
        int i = (idx >> 8) & 255, js = idx & 255;
        int jl = js ^ ((i & 7) << 3);
        int d = (i - jl) & 255;
        int m = 2 * US[u] + 1;
        float h;
        if (d == 0) {
            h = (float)m * (1.0f / 256.0f);
        } else {
            int t = (m * d) & 511;
            float num = sinf((float)t * (PI_F / 256.0f));
            float den = sinf((float)d * (PI_F / 256.0f));
            h = num / (256.0f * den);
        }
        H[idx] = f2bf(h);
    } else {
        int idx = (b - 2048) * 256 + threadIdx.x;   // u16x4 units
        f32x4 v = ((const f32x4*)x)[idx];
        u16x4 o = { f2bf(v.x), f2bf(v.y), f2bf(v.z), f2bf(v.w) };
        int n = idx >> 14;
        int t = idx & 16383;
        int i = t >> 6;
        int jlin = (t & 63) * 4;
        int js = jlin ^ ((i & 7) << 3);
        *(u16x4*)(Xb + (size_t)n * 65536 + i * 256 + js) = o;
        if (write_c0) {
            size_t g = (size_t)idx * 4;
            out[(g + 0) * 9] = v.x;
            out[(g + 1) * 9] = v.y;
            out[(g + 2) * 9] = v.z;
            out[(g + 3) * 9] = v.w;
        }
    }
}

// stage12: fused T_u = X*H_u (phase A -> LDS) and Z_u = H_u*T_u (phase B -> Zb).
// Block = (n, u, jq quarter), 256 threads (4 waves), LDS 72 KB -> 2 blocks/CU.
// Sync structure is EXACTLY round-5's verified pattern (no cross-phase prefetch).
__global__ void __launch_bounds__(256) stage12(const unsigned short* __restrict__ Xb,
                                               const unsigned short* __restrict__ H,
                                               unsigned short* __restrict__ Zb,
                                               float* __restrict__ fOut,
                                               int mode, int u_fixed) {
    extern __shared__ char smem[];
    char* sStage = smem;            // 32KB: 256 rows x 128B (X quarter / H quarter-K)
    char* sHq    = smem + 32768;    //  8KB:  64 rows x 128B (H j-quarter rows)
    char* sT     = smem + 40960;    // 32KB:  64 rows x 512B (T^T, swizzled)

    int n, u, jq;
    if (u_fixed >= 0) {
        n = blockIdx.x >> 2; jq = blockIdx.x & 3; u = u_fixed;
    } else {
        int swz = (blockIdx.x & 7) * 256 + (blockIdx.x >> 3);  // XCD-chunked, bijective
        n = swz >> 5; u = (swz >> 2) & 7; jq = swz & 3;
    }

    const char* Xn = (const char*)(Xb + (size_t)n * 65536);
    const char* Hu = (const char*)(H + (size_t)u * 65536);

    const int tid  = threadIdx.x;
    const int lane = tid & 63;
    const int w    = tid >> 6;        // 0..3
    const int lrow = lane & 15;
    const int lk   = lane >> 4;
    const int srow = lane >> 3, sch = lane & 7;

    f32x4 acc[4][4];
#pragma unroll
    for (int a = 0; a < 4; ++a)
#pragma unroll
        for (int b = 0; b < 4; ++b) acc[a][b] = (f32x4){0.f, 0.f, 0.f, 0.f};

    // ---------------- phase A: sT[jl][i] = T[i, jq*64+jl] ----------------
    for (int kt = 0; kt < 4; ++kt) {
        if (kt) __syncthreads();
#pragma unroll
        for (int q = 0; q < 8; ++q) {      // X rows 0..255 (kt-quarter)
            int r = (w * 8 + q) * 8 + srow;
            gload16(Xn + r * 512 + kt * 128 + sch * 16, sStage + (w * 8 + q) * 1024);
        }
#pragma unroll
        for (int q = 0; q < 2; ++q) {      // H rows jq*64 .. +63
            int r = jq * 64 + (w * 2 + q) * 8 + srow;
            gload16(Hu + r * 512 + kt * 128 + sch * 16, sHq + (w * 2 + q) * 1024);
        }
        __syncthreads();                    // drains vmcnt(0)
#pragma unroll
        for (int kk = 0; kk < 2; ++kk) {
            const int kb = kk * 64 + lk * 16;
            u32x4 af[4], bf[4];
#pragma unroll
            for (int mi = 0; mi < 4; ++mi)
                af[mi] = *(const u32x4*)(sStage + SWZ(w * 64 + mi * 16 + lrow, kb));
#pragma unroll
            for (int ni = 0; ni < 4; ++ni)
                bf[ni] = *(const u32x4*)(sHq + SWZ(ni * 16 + lrow, kb));
#pragma unroll
            for (int mi = 0; mi < 4; ++mi)
#pragma unroll
                for (int ni = 0; ni < 4; ++ni)
                    mfma16(acc[mi][ni], af[mi], bf[ni]);
        }
    }
    asm volatile("s_nop 7\n\ts_nop 7");

    // epilogue A -> sT (bf16, row jl stride 512B, byte 2i ^ ((jl&7)<<4))
#pragma unroll
    for (int mi = 0; mi < 4; ++mi) {
        int i4 = w * 64 + mi * 16 + (lane >> 4) * 4;
#pragma unroll
        for (int ni = 0; ni < 4; ++ni) {
            int jl = ni * 16 + lrow;
            u16x4 o = { f2bf(acc[mi][ni].x), f2bf(acc[mi][ni].y),
                        f2bf(acc[mi][ni].z), f2bf(acc[mi][ni].w) };
            *(u16x4*)(sT + jl * 512 + ((2 * i4) ^ ((jl & 7) << 4))) = o;
        }
    }
    __syncthreads();   // sT visible; all phase-A sStage/sHq reads drained

    // ---------------- phase B: Z[i, jg] = sum_m sT[jl,m] H[i,m] ----------------
#pragma unroll
    for (int a = 0; a < 4; ++a)
#pragma unroll
        for (int b = 0; b < 4; ++b) acc[a][b] = (f32x4){0.f, 0.f, 0.f, 0.f};

    for (int kt = 0; kt < 4; ++kt) {
        if (kt) __syncthreads();
#pragma unroll
        for (int q = 0; q < 8; ++q) {      // H rows 0..255 (kt-quarter)
            int r = (w * 8 + q) * 8 + srow;
            gload16(Hu + r * 512 + kt * 128 + sch * 16, sStage + (w * 8 + q) * 1024);
        }
        __syncthreads();
#pragma unroll
        for (int kk = 0; kk < 2; ++kk) {
            const int kb  = kk * 64 + lk * 16;
            const int kbT = kt * 128 + kb;
            u32x4 af[4], bf[4];
#pragma unroll
            for (int mi = 0; mi < 4; ++mi) {
                int r = mi * 16 + lrow;
                af[mi] = *(const u32x4*)(sT + r * 512 + (kbT ^ ((r & 7) << 4)));
            }
#pragma unroll
            for (int ni = 0; ni < 4; ++ni)
                bf[ni] = *(const u32x4*)(sStage + SWZ(w * 64 + ni * 16 + lrow, kb));
#pragma unroll
            for (int mi = 0; mi < 4; ++mi)
#pragma unroll
                for (int ni = 0; ni < 4; ++ni)
                    mfma16(acc[mi][ni], af[mi], bf[ni]);
        }
    }
    asm volatile("s_nop 7\n\ts_nop 7");

    if (mode == 0) {
        unsigned short* Op = Zb + ((size_t)(u * 64 + n)) * 65536 + jq * 64;
#pragma unroll
        for (int mi = 0; mi < 4; ++mi) {
            int r4 = mi * 16 + (lane >> 4) * 4;          // jl (4 consecutive)
#pragma unroll
            for (int ni = 0; ni < 4; ++ni) {
                int c = w * 64 + ni * 16 + lrow;         // i
                u16x4 o = { f2bf(acc[mi][ni].x), f2bf(acc[mi][ni].y),
                            f2bf(acc[mi][ni].z), f2bf(acc[mi][ni].w) };
                *(u16x4*)(Op + (size_t)c * 256 + r4) = o;
            }
        }
    } else {
#pragma unroll
        for (int mi = 0; mi < 4; ++mi) {
            int r4 = mi * 16 + (lane >> 4) * 4;
#pragma unroll
            for (int ni = 0; ni < 4; ++ni) {
                int c = w * 64 + ni * 16 + lrow;
                float* o = fOut + (((size_t)n * 256 + c) * 256 + jq * 64 + r4) * 9 + 1 + u;
                o[0]  = acc[mi][ni].x;
                o[9]  = acc[mi][ni].y;
                o[18] = acc[mi][ni].z;
                o[27] = acc[mi][ni].w;
            }
        }
    }
}

// pack9: out[p*9+0]=x[p]; out[p*9+1+u]=Zb[u][p]; contiguous dwordx4 stores.
__global__ void __launch_bounds__(256) pack9(const float* __restrict__ x,
                                             const unsigned short* __restrict__ Zb,
                                             float* __restrict__ out) {
    __shared__ float sl[9216];
    const int t = threadIdx.x;
    const size_t g0 = (size_t)blockIdx.x * 1024;

#pragma unroll
    for (int c = 0; c < 2; ++c) {
        int q = c * 512 + t * 2;
        size_t p = g0 + q;
        f32x2 xv = *(const f32x2*)(x + p);
        sl[q * 9]       = xv.x;
        sl[(q + 1) * 9] = xv.y;
#pragma unroll
        for (int u = 0; u < 8; ++u) {
            u16x2 z = *(const u16x2*)(Zb + (size_t)u * 4194304 + p);
            sl[q * 9 + 1 + u]       = bf2f(z.x);
            sl[(q + 1) * 9 + 1 + u] = bf2f(z.y);
        }
    }
    __syncthreads();
    float* ob = out + g0 * 9;
#pragma unroll
    for (int r = 0; r < 9; ++r) {
        int d = r * 1024 + t * 4;
        *(f32x4*)(ob + d) = *(const f32x4*)&sl[d];
    }
}

extern "C" void kernel_launch(void* const* d_in, const int* in_sizes, int n_in,
                              void* d_out, int out_size, void* d_ws, size_t ws_size,
                              hipStream_t stream) {
    const float* x = (const float*)d_in[0];
    float* out = (float*)d_out;
    char* ws = (char*)d_ws;

    unsigned short* H  = (unsigned short*)(ws);                // 1 MB
    unsigned short* Xb = (unsigned short*)(ws + 1048576);      // 8 MB
    unsigned short* Zb = (unsigned short*)(ws + 9437184);      // 64 MB

    const size_t NEED_FULL = 76546048ull;   // H + Xb + Zb
    const size_t LDS_BYTES = 73728;         // 72 KB dynamic -> 2 blocks/CU

    if (ws_size >= NEED_FULL) {
        prep<<<6144, 256, 0, stream>>>(x, H, Xb, out, 0);
        stage12<<<2048, 256, LDS_BYTES, stream>>>(Xb, H, Zb, nullptr, 0, -1);
        pack9<<<4096, 256, 0, stream>>>(x, Zb, out);
    } else {
        // minimal-ws fallback (9 MB): per-u, fp32 scatter epilogue
        prep<<<6144, 256, 0, stream>>>(x, H, Xb, out, 1);
        for (int u = 0; u < 8; ++u)
            stage12<<<256, 256, LDS_BYTES, stream>>>(Xb, H, nullptr, out, 1, u);
    }
}